// Round 4
// baseline (211.792 us; speedup 1.0000x reference)
//
#include <hip/hip_runtime.h>

// Dynamic voxelization: coors[d, i] = valid ? floor((p[i,d]-mn[d])/vs[d]) : -1
// Memory-bound streaming kernel: 128 MB read + 96 MB write, no reuse.
// 4 points per thread: 4x 16B loads (64B/lane), 3x 16B stores (48B/lane).
// Nontemporal hints: pure streaming, keep L2/L3 clean.
// NOTE: __builtin_nontemporal_* requires native clang vector types (not
// HIP_vector_type), and ext_vector elements can't bind to references ->
// voxel_one returns by value.

typedef float fx4 __attribute__((ext_vector_type(4)));
typedef int   ix4 __attribute__((ext_vector_type(4)));

#define VS_X 0.05f
#define VS_Y 0.05f
#define VS_Z 0.1f
#define MN_X 0.0f
#define MN_Y -40.0f
#define MN_Z -3.0f
#define GX 1408
#define GY 1600
#define GZ 40

struct Coor { int x, y, z; };

__device__ __forceinline__ Coor voxel_one(fx4 p) {
    // Match reference numerics: fp32 subtract, fp32 IEEE divide, floor, trunc.
    int x = (int)floorf((p.x - MN_X) / VS_X);
    int y = (int)floorf((p.y - MN_Y) / VS_Y);
    int z = (int)floorf((p.z - MN_Z) / VS_Z);
    bool valid = (x >= 0) & (x < GX) & (y >= 0) & (y < GY) & (z >= 0) & (z < GZ);
    Coor c;
    c.x = valid ? x : -1;
    c.y = valid ? y : -1;
    c.z = valid ? z : -1;
    return c;
}

__global__ __launch_bounds__(256) void voxelize_kernel(
    const fx4* __restrict__ points, int* __restrict__ out, int n) {
    int t = blockIdx.x * blockDim.x + threadIdx.x;
    int base = t * 4;
    if (base >= n) return;

    int* out_x = out;
    int* out_y = out + n;
    int* out_z = out + 2 * n;

    if (base + 3 < n) {
        fx4 p0 = __builtin_nontemporal_load(&points[base + 0]);
        fx4 p1 = __builtin_nontemporal_load(&points[base + 1]);
        fx4 p2 = __builtin_nontemporal_load(&points[base + 2]);
        fx4 p3 = __builtin_nontemporal_load(&points[base + 3]);

        Coor c0 = voxel_one(p0);
        Coor c1 = voxel_one(p1);
        Coor c2 = voxel_one(p2);
        Coor c3 = voxel_one(p3);

        ix4 vx = {c0.x, c1.x, c2.x, c3.x};
        ix4 vy = {c0.y, c1.y, c2.y, c3.y};
        ix4 vz = {c0.z, c1.z, c2.z, c3.z};

        __builtin_nontemporal_store(vx, (ix4*)&out_x[base]);
        __builtin_nontemporal_store(vy, (ix4*)&out_y[base]);
        __builtin_nontemporal_store(vz, (ix4*)&out_z[base]);
    } else {
        for (int i = base; i < n; ++i) {
            fx4 p = points[i];
            Coor c = voxel_one(p);
            out_x[i] = c.x;
            out_y[i] = c.y;
            out_z[i] = c.z;
        }
    }
}

extern "C" void kernel_launch(void* const* d_in, const int* in_sizes, int n_in,
                              void* d_out, int out_size, void* d_ws, size_t ws_size,
                              hipStream_t stream) {
    const fx4* points = (const fx4*)d_in[0];
    int* out = (int*)d_out;
    int n = in_sizes[0] / 4;  // points is (N, 4) flat

    int block = 256;
    int n_threads = (n + 3) / 4;
    int grid = (n_threads + block - 1) / block;
    voxelize_kernel<<<grid, block, 0, stream>>>(points, out, n);
}

// Round 5
// 199.510 us; speedup vs baseline: 1.0616x; 1.0616x over previous
//
#include <hip/hip_runtime.h>

// Dynamic voxelization: coors[d, i] = valid ? floor((p[i,d]-mn[d])/vs[d]) : -1
// Memory-bound streaming: 128 MB read + 96 MB write, no reuse. Floor ~33 us
// at 6.8 TB/s; harness restore (~130 us/iter) dominates bench dur_us.
// Round-1 structure (best measured): 1 point/thread, float4 load (16B/lane),
// 3 dense 4B stores. NT hints: pure streaming, don't allocate in L2.
// Numerics must match np reference: fp32 sub, IEEE fp32 div, floorf, trunc
// (reciprocal-multiply risks a validity flip at grid boundary -> absmax 1600).

typedef float fx4 __attribute__((ext_vector_type(4)));

#define VS_X 0.05f
#define VS_Y 0.05f
#define VS_Z 0.1f
#define MN_X 0.0f
#define MN_Y -40.0f
#define MN_Z -3.0f
#define GX 1408
#define GY 1600
#define GZ 40

__global__ __launch_bounds__(256) void voxelize_kernel(
    const fx4* __restrict__ points, int* __restrict__ out, int n) {
    int i = blockIdx.x * blockDim.x + threadIdx.x;
    if (i >= n) return;

    fx4 p = __builtin_nontemporal_load(&points[i]);

    int cx = (int)floorf((p.x - MN_X) / VS_X);
    int cy = (int)floorf((p.y - MN_Y) / VS_Y);
    int cz = (int)floorf((p.z - MN_Z) / VS_Z);

    bool valid = (cx >= 0) & (cx < GX) & (cy >= 0) & (cy < GY) & (cz >= 0) & (cz < GZ);

    __builtin_nontemporal_store(valid ? cx : -1, &out[i]);
    __builtin_nontemporal_store(valid ? cy : -1, &out[n + i]);
    __builtin_nontemporal_store(valid ? cz : -1, &out[2 * n + i]);
}

extern "C" void kernel_launch(void* const* d_in, const int* in_sizes, int n_in,
                              void* d_out, int out_size, void* d_ws, size_t ws_size,
                              hipStream_t stream) {
    const fx4* points = (const fx4*)d_in[0];
    int* out = (int*)d_out;
    int n = in_sizes[0] / 4;  // points is (N, 4) flat

    int block = 256;
    int grid = (n + block - 1) / block;
    voxelize_kernel<<<grid, block, 0, stream>>>(points, out, n);
}